// Round 1
// baseline (161.868 us; speedup 1.0000x reference)
//
#include <hip/hip_runtime.h>

#define THR_F     0.2f
#define TANH_THR  0.19737532f   // tanh(0.2), fp32-rounded

// ---------------------------------------------------------------------------
// helpers
// ---------------------------------------------------------------------------
__device__ __forceinline__ float fast_tanh(float x) {
    x = fminf(10.f, fmaxf(-10.f, x));
    float e = __expf(2.f * x);
    return (e - 1.f) * __builtin_amdgcn_rcpf(e + 1.f);
}

// monotone float <-> uint key for atomicMax on floats
__device__ __forceinline__ unsigned fkey(float f) {
    unsigned u = __float_as_uint(f);
    return (u & 0x80000000u) ? ~u : (u | 0x80000000u);
}
__device__ __forceinline__ float fdecode(unsigned u) {
    return __uint_as_float((u & 0x80000000u) ? (u & 0x7FFFFFFFu) : ~u);
}

// ---------------------------------------------------------------------------
// Kernel 0: pack weights, compute base[b][ac] = N + and_bias, init max ws
// and_kernel layout: (3,8,640) -> ac = a*8+c rows of 640
//   cols 0:128 nullary | 128:256 u(o0) | 256:384 u(o1) | 384:512 b(o0,j01) | 512:640 b(o1,j10)
// ---------------------------------------------------------------------------
__global__ __launch_bounds__(256) void prep_kernel(
    const float* __restrict__ nullary,   // [16][128]
    const float* __restrict__ andk,      // [24][640]
    float* __restrict__ Wb,              // [128][48] packed binary weights
    float* __restrict__ Wu,              // [128][48] packed unary weights
    float* __restrict__ base,            // [16][24]
    unsigned* __restrict__ max0)         // [16][8]
{
    const int t = threadIdx.x;
    // pack weights: W[k][n], n<24 -> first slice (ac=n), n>=24 -> second slice
    for (int i = t; i < 6144; i += 256) {
        int k = i / 48, n = i % 48;
        int ac   = (n < 24) ? n : n - 24;
        int colb = (n < 24) ? 384 : 512;
        int colu = (n < 24) ? 128 : 256;
        Wb[i] = andk[ac * 640 + colb + k];
        Wu[i] = andk[ac * 640 + colu + k];
    }
    if (t < 128) max0[t] = 0u;   // 0 is the minimum key

    __shared__ float ssq[24];
    if (t < 24) {
        float s = 0.f;
        const float* w = andk + t * 640;
        for (int i = 0; i < 640; ++i) s = fmaf(w[i], w[i], s);
        ssq[t] = s;
    }
    __syncthreads();

    // base[b][n] = dot(nullary[b], K[n,0:128]) + THR - ssq[n]*tanh(THR)
    for (int task = t; task < 384; task += 256) {
        int b = task / 24, n = task % 24;
        const float* nu = nullary + b * 128;
        const float* w  = andk + n * 640;
        float s = 0.f;
        for (int i = 0; i < 128; ++i) s = fmaf(nu[i], w[i], s);
        base[task] = s + THR_F - ssq[n] * TANH_THR;
    }
}

// ---------------------------------------------------------------------------
// Kernel 1: projections. 1 row (128 floats) per thread, 48 outputs per row.
// blocks 0..251: binary rows (64512); blocks 252..255: unary rows (1024).
// Weight loads have wave-uniform addresses -> scalar (s_load) path.
// ---------------------------------------------------------------------------
__global__ __launch_bounds__(256) void proj_kernel(
    const float* __restrict__ unary,     // [1024][128]
    const float* __restrict__ binary,    // [64512][128]
    const float* __restrict__ Wb,        // [128][48]
    const float* __restrict__ Wu,        // [128][48]
    float* __restrict__ P0, float* __restrict__ P1,   // [64512][24] each
    float* __restrict__ U0, float* __restrict__ U1)   // [1024][24] each
{
    const int bid = blockIdx.x;
    const bool is_bin = (bid < 252);
    const float* __restrict__ W = is_bin ? Wb : Wu;
    int row;
    const float* src;
    float *D0, *D1;
    if (is_bin) {
        row = bid * 256 + threadIdx.x;
        src = binary + (size_t)row * 128;
        D0 = P0 + (size_t)row * 24;
        D1 = P1 + (size_t)row * 24;
    } else {
        row = (bid - 252) * 256 + threadIdx.x;
        src = unary + (size_t)row * 128;
        D0 = U0 + (size_t)row * 24;
        D1 = U1 + (size_t)row * 24;
    }

    float acc[48];
#pragma unroll
    for (int n = 0; n < 48; ++n) acc[n] = 0.f;

    const float4* rp = (const float4*)src;
#pragma unroll 2
    for (int k4 = 0; k4 < 32; ++k4) {
        float4 a = rp[k4];
        const float* wk = W + k4 * 4 * 48;
#pragma unroll
        for (int q = 0; q < 4; ++q) {
            float av = (q == 0) ? a.x : (q == 1) ? a.y : (q == 2) ? a.z : a.w;
            const float* w = wk + q * 48;
#pragma unroll
            for (int n = 0; n < 48; ++n) acc[n] = fmaf(av, w[n], acc[n]);
        }
    }

    float4* d0 = (float4*)D0;
    float4* d1 = (float4*)D1;
#pragma unroll
    for (int i = 0; i < 6; ++i) {
        d0[i] = make_float4(acc[i*4+0], acc[i*4+1], acc[i*4+2], acc[i*4+3]);
        d1[i] = make_float4(acc[24+i*4+0], acc[24+i*4+1], acc[24+i*4+2], acc[24+i*4+3]);
    }
}

// ---------------------------------------------------------------------------
// Kernel 2: combine + tanh + reductions + OR stage.
// grid = 1024 blocks (b,o0), block = 64 threads (one wave), thread t -> o1.
// perm p = o0*63 + j01, j01 = t, o1 = t + (t>=o0), j10 = o0 - (o0>o1).
// ---------------------------------------------------------------------------
__global__ __launch_bounds__(64) void combine_kernel(
    const float* __restrict__ base,   // [16][24]
    const float* __restrict__ U0, const float* __restrict__ U1,  // [1024][24]
    const float* __restrict__ P0, const float* __restrict__ P1,  // [64512][24]
    const float* __restrict__ ork,    // [3][8]
    unsigned* __restrict__ max0,      // [16][8]
    float* __restrict__ out)          // [16] + [1024] + [64512]
{
    const int bid = blockIdx.x;
    const int b  = bid >> 6;
    const int o0 = bid & 63;
    const int t  = threadIdx.x;
    const bool act = (t < 63);

    const int o1  = min(t + (t >= o0 ? 1 : 0), 63);
    const int j10 = (o1 < o0) ? (o0 - 1) : o0;
    const int j01 = min(t, 62);

    const float* pb  = base + b * 24;                                  // uniform
    const float* pa0 = U0 + (size_t)(b * 64 + o0) * 24;                // uniform
    const float4* A1 = (const float4*)(U1 + (size_t)(b * 64 + o1) * 24);
    const float4* Q0 = (const float4*)(P0 + (size_t)((b * 64 + o0) * 63 + j01) * 24);
    const float4* Q1 = (const float4*)(P1 + (size_t)((b * 64 + o1) * 63 + j10) * 24);

    float th[24];
#pragma unroll
    for (int i = 0; i < 6; ++i) {
        float4 a1 = A1[i], q0 = Q0[i], q1 = Q1[i];
        int n = i * 4;
        th[n+0] = pb[n+0] + pa0[n+0] + a1.x + q0.x + q1.x;
        th[n+1] = pb[n+1] + pa0[n+1] + a1.y + q0.y + q1.y;
        th[n+2] = pb[n+2] + pa0[n+2] + a1.z + q0.z + q1.z;
        th[n+3] = pb[n+3] + pa0[n+3] + a1.w + q0.w + q1.w;
    }
#pragma unroll
    for (int n = 0; n < 24; ++n) th[n] = fast_tanh(th[n]);

    // out2 (a=2): direct OR over c
    if (act) {
        float v = 0.f, b2 = 0.f;
#pragma unroll
        for (int c = 0; c < 8; ++c) {
            float k = ork[16 + c];
            v  = fmaf(th[16 + c], k, v);
            b2 = fmaf(k, k, b2);
        }
        out[16 + 1024 + ((b * 64 + o0) * 63 + t)] = v + b2 * TANH_THR - THR_F;
    }

    // mask inactive lane for the max reductions
    if (!act) {
#pragma unroll
        for (int n = 0; n < 16; ++n) th[n] = -2.0f;
    }

    // wave-wide max over the 63 perms for channels 0..15 (a=0 and a=1)
#pragma unroll
    for (int n = 0; n < 16; ++n) {
        float v = th[n];
#pragma unroll
        for (int m = 32; m; m >>= 1) v = fmaxf(v, __shfl_xor(v, m, 64));
        th[n] = v;
    }

    if (t == 0) {
        // out1 (a=1): max over o1 done; OR over c
        float v1 = 0.f, b1 = 0.f;
#pragma unroll
        for (int c = 0; c < 8; ++c) {
            float k = ork[8 + c];
            v1 = fmaf(th[8 + c], k, v1);
            b1 = fmaf(k, k, b1);
        }
        out[16 + b * 64 + o0] = v1 + b1 * TANH_THR - THR_F;
        // out0 (a=0): global max across all perms via atomicMax on ordered keys
#pragma unroll
        for (int c = 0; c < 8; ++c)
            atomicMax(&max0[b * 8 + c], fkey(th[c]));
    }
}

// ---------------------------------------------------------------------------
// Kernel 3: finalize out0 from the atomicMax workspace
// ---------------------------------------------------------------------------
__global__ __launch_bounds__(64) void finalize_kernel(
    const unsigned* __restrict__ max0,
    const float* __restrict__ ork,
    float* __restrict__ out)
{
    int b = threadIdx.x;
    if (b >= 16) return;
    float v = 0.f, bb = 0.f;
#pragma unroll
    for (int c = 0; c < 8; ++c) {
        float m = fdecode(max0[b * 8 + c]);
        float k = ork[c];
        v  = fmaf(m, k, v);
        bb = fmaf(k, k, bb);
    }
    out[b] = v + bb * TANH_THR - THR_F;
}

// ---------------------------------------------------------------------------
// launcher
// ---------------------------------------------------------------------------
extern "C" void kernel_launch(void* const* d_in, const int* in_sizes, int n_in,
                              void* d_out, int out_size, void* d_ws, size_t ws_size,
                              hipStream_t stream)
{
    const float* nullary = (const float*)d_in[0];   // (16,128)
    const float* unary   = (const float*)d_in[1];   // (16,64,128)
    const float* binary  = (const float*)d_in[2];   // (16,64,63,128)
    const float* andk    = (const float*)d_in[3];   // (3,8,640)
    const float* ork     = (const float*)d_in[4];   // (3,8)
    float* out = (float*)d_out;

    float* ws = (float*)d_ws;
    float*    base = ws;                         // 384
    float*    U0   = ws + 384;                   // 24576
    float*    U1   = ws + 24960;                 // 24576
    float*    Wb   = ws + 49536;                 // 6144
    float*    Wu   = ws + 55680;                 // 6144
    float*    P0   = ws + 61824;                 // 1548288
    float*    P1   = ws + 1610112;               // 1548288
    unsigned* max0 = (unsigned*)(ws + 3158400);  // 128 u32

    prep_kernel<<<1, 256, 0, stream>>>(nullary, andk, Wb, Wu, base, max0);
    proj_kernel<<<256, 256, 0, stream>>>(unary, binary, Wb, Wu, P0, P1, U0, U1);
    combine_kernel<<<1024, 64, 0, stream>>>(base, U0, U1, P0, P1, ork, max0, out);
    finalize_kernel<<<1, 64, 0, stream>>>(max0, ork, out);
}

// Round 2
// 126.190 us; speedup vs baseline: 1.2827x; 1.2827x over previous
//
#include <hip/hip_runtime.h>

#define THR_F     0.2f
#define TANH_THR  0.19737532f   // tanh(0.2), fp32-rounded

// ---------------------------------------------------------------------------
// helpers
// ---------------------------------------------------------------------------
__device__ __forceinline__ float fast_tanh(float x) {
    x = fminf(10.f, fmaxf(-10.f, x));
    float e = __expf(2.f * x);
    return (e - 1.f) * __builtin_amdgcn_rcpf(e + 1.f);
}

// monotone float <-> uint key for atomicMax on floats
__device__ __forceinline__ unsigned fkey(float f) {
    unsigned u = __float_as_uint(f);
    return (u & 0x80000000u) ? ~u : (u | 0x80000000u);
}
__device__ __forceinline__ float fdecode(unsigned u) {
    return __uint_as_float((u & 0x80000000u) ? (u & 0x7FFFFFFFu) : ~u);
}

// ---------------------------------------------------------------------------
// Kernel 0: prep. Grid = 480 blocks x 64 threads (one wave each).
//  blocks 0..383   : (b,n)=bid -> base[b*24+n] = dot(nullary[b],K[n,0:128])
//                    + THR - ssq[n]*tanh(THR)   (ssq recomputed per block)
//  blocks 384..479 : pack Wb/Wu (6144 elems, 64/block); blocks 384-385 also
//                    zero the 128-entry atomicMax workspace.
// and_kernel layout: (3,8,640) -> ac = a*8+c rows of 640
//   cols 0:128 null | 128:256 u(o0) | 256:384 u(o1) | 384:512 b(o0,j01) | 512:640 b(o1,j10)
// ---------------------------------------------------------------------------
__global__ __launch_bounds__(64) void prep_kernel(
    const float* __restrict__ nullary,   // [16][128]
    const float* __restrict__ andk,      // [24][640]
    float* __restrict__ Wb,              // [128][48] packed binary weights
    float* __restrict__ Wu,              // [128][48] packed unary weights
    float* __restrict__ base,            // [16][24]
    unsigned* __restrict__ max0)         // [16][8]
{
    const int bid = blockIdx.x;
    const int t   = threadIdx.x;
    if (bid < 384) {
        const int b = bid / 24, n = bid % 24;
        const float* w  = andk + n * 640;
        const float* nu = nullary + b * 128;
        float s = 0.f;
        #pragma unroll
        for (int i = 0; i < 10; ++i) { float v = w[t + i * 64]; s = fmaf(v, v, s); }
        float d = fmaf(nu[t], w[t], 0.f);
        d = fmaf(nu[t + 64], w[t + 64], d);
        #pragma unroll
        for (int m = 32; m; m >>= 1) {
            s += __shfl_xor(s, m, 64);
            d += __shfl_xor(d, m, 64);
        }
        if (t == 0) base[bid] = d + THR_F - s * TANH_THR;
    } else {
        const int i = (bid - 384) * 64 + t;   // 0..6143
        const int k = i / 48, n = i % 48;
        const int ac   = (n < 24) ? n : n - 24;
        const int colb = (n < 24) ? 384 : 512;
        const int colu = (n < 24) ? 128 : 256;
        Wb[i] = andk[ac * 640 + colb + k];
        Wu[i] = andk[ac * 640 + colu + k];
        if (bid < 386) max0[(bid - 384) * 64 + t] = 0u;
    }
}

// ---------------------------------------------------------------------------
// Kernel 1: projections. Grid = 1024 blocks x 256 threads (4 waves).
//  blocks 0..1007: binary rows (64 rows/block); 1008..1023: unary rows.
//  Wave w (wave-uniform via readfirstlane) computes a 12-channel slice:
//    w=0: P0/U0 ch 0..11, w=1: P0/U0 ch 12..23, w=2: P1/U1 ch 0..11, w=3: ch 12..23
//  Lane = row. Weight pointer is wave-uniform -> scalar (s_load) path, so the
//  inner loop is pure v_fmac with SGPR operands.
// ---------------------------------------------------------------------------
__global__ __launch_bounds__(256) void proj_kernel(
    const float* __restrict__ unary,     // [1024][128]
    const float* __restrict__ binary,    // [64512][128]
    const float* __restrict__ Wb,        // [128][48]
    const float* __restrict__ Wu,        // [128][48]
    float* __restrict__ P0, float* __restrict__ P1,   // [64512][24] each
    float* __restrict__ U0, float* __restrict__ U1)   // [1024][24] each
{
    const int bid  = blockIdx.x;
    const int wave = __builtin_amdgcn_readfirstlane((int)(threadIdx.x >> 6)); // 0..3
    const int lane = threadIdx.x & 63;
    const bool is_bin = (bid < 1008);

    const int row = is_bin ? (bid * 64 + lane) : ((bid - 1008) * 64 + lane);
    const float* __restrict__ W   = (is_bin ? Wb : Wu) + wave * 12;
    const float* __restrict__ src = (is_bin ? binary : unary) + (size_t)row * 128;
    float* Dbase = is_bin ? ((wave < 2) ? P0 : P1) : ((wave < 2) ? U0 : U1);
    float* dst = Dbase + (size_t)row * 24 + (wave & 1) * 12;

    float acc[12];
    #pragma unroll
    for (int n = 0; n < 12; ++n) acc[n] = 0.f;

    const float4* rp = (const float4*)src;
    #pragma unroll 8
    for (int k4 = 0; k4 < 32; ++k4) {
        float4 a = rp[k4];
        const float* wk = W + k4 * 4 * 48;
        #pragma unroll
        for (int q = 0; q < 4; ++q) {
            float av = (q == 0) ? a.x : (q == 1) ? a.y : (q == 2) ? a.z : a.w;
            const float* w = wk + q * 48;
            #pragma unroll
            for (int n = 0; n < 12; ++n) acc[n] = fmaf(av, w[n], acc[n]);
        }
    }

    float4* d4 = (float4*)dst;
    #pragma unroll
    for (int i = 0; i < 3; ++i)
        d4[i] = make_float4(acc[i*4+0], acc[i*4+1], acc[i*4+2], acc[i*4+3]);
}

// ---------------------------------------------------------------------------
// Kernel 2: combine + tanh + reductions + OR stage.
// Grid = 1024 blocks (b,o0) x 192 threads (3 waves). Wave a handles OR-stage a
// (8 channels, ch = a*8) — no inter-wave communication needed:
//   a=0: wave-max over perms -> atomicMax (global max over all perms)
//   a=1: wave-max over o1 -> OR dot -> out1[b,o0]
//   a=2: direct OR dot -> out2[b,o0,j01] per lane
// lane t -> o1 = t + (t>=o0), j01 = t, j10 = o0 - (o0>o1).
// ---------------------------------------------------------------------------
__global__ __launch_bounds__(192) void combine_kernel(
    const float* __restrict__ base,   // [16][24]
    const float* __restrict__ U0, const float* __restrict__ U1,  // [1024][24]
    const float* __restrict__ P0, const float* __restrict__ P1,  // [64512][24]
    const float* __restrict__ ork,    // [3][8]
    unsigned* __restrict__ max0,      // [16][8]
    float* __restrict__ out)          // [16] + [1024] + [64512]
{
    const int bid = blockIdx.x;
    const int b   = bid >> 6;
    const int o0  = bid & 63;
    const int a   = __builtin_amdgcn_readfirstlane((int)(threadIdx.x >> 6)); // 0..2
    const int t   = threadIdx.x & 63;
    const bool act = (t < 63);

    const int o1  = min(t + (t >= o0 ? 1 : 0), 63);
    const int j10 = (o1 < o0) ? (o0 - 1) : o0;
    const int j01 = min(t, 62);
    const int ch  = a * 8;

    const float* pb  = base + b * 24 + ch;                                  // uniform
    const float* pa0 = U0 + (size_t)(b * 64 + o0) * 24 + ch;                // uniform
    const float4* A1 = (const float4*)(U1 + (size_t)(b * 64 + o1) * 24 + ch);
    const float4* Q0 = (const float4*)(P0 + (size_t)((b * 64 + o0) * 63 + j01) * 24 + ch);
    const float4* Q1 = (const float4*)(P1 + (size_t)((b * 64 + o1) * 63 + j10) * 24 + ch);

    float th[8];
    #pragma unroll
    for (int i = 0; i < 2; ++i) {
        float4 a1 = A1[i], q0 = Q0[i], q1 = Q1[i];
        int n = i * 4;
        th[n+0] = pb[n+0] + pa0[n+0] + a1.x + q0.x + q1.x;
        th[n+1] = pb[n+1] + pa0[n+1] + a1.y + q0.y + q1.y;
        th[n+2] = pb[n+2] + pa0[n+2] + a1.z + q0.z + q1.z;
        th[n+3] = pb[n+3] + pa0[n+3] + a1.w + q0.w + q1.w;
    }
    #pragma unroll
    for (int n = 0; n < 8; ++n) th[n] = fast_tanh(th[n]);

    if (a == 2) {
        if (act) {
            float v = 0.f, b2 = 0.f;
            #pragma unroll
            for (int c = 0; c < 8; ++c) {
                float k = ork[16 + c];
                v  = fmaf(th[c], k, v);
                b2 = fmaf(k, k, b2);
            }
            out[16 + 1024 + ((b * 64 + o0) * 63 + t)] = v + b2 * TANH_THR - THR_F;
        }
        return;
    }

    // mask inactive lane for the max reductions
    if (!act) {
        #pragma unroll
        for (int n = 0; n < 8; ++n) th[n] = -2.0f;
    }
    #pragma unroll
    for (int n = 0; n < 8; ++n) {
        float v = th[n];
        #pragma unroll
        for (int m = 32; m; m >>= 1) v = fmaxf(v, __shfl_xor(v, m, 64));
        th[n] = v;
    }

    if (t == 0) {
        if (a == 1) {
            float v1 = 0.f, b1 = 0.f;
            #pragma unroll
            for (int c = 0; c < 8; ++c) {
                float k = ork[8 + c];
                v1 = fmaf(th[c], k, v1);
                b1 = fmaf(k, k, b1);
            }
            out[16 + b * 64 + o0] = v1 + b1 * TANH_THR - THR_F;
        } else {
            #pragma unroll
            for (int c = 0; c < 8; ++c)
                atomicMax(&max0[b * 8 + c], fkey(th[c]));
        }
    }
}

// ---------------------------------------------------------------------------
// Kernel 3: finalize out0 from the atomicMax workspace
// ---------------------------------------------------------------------------
__global__ __launch_bounds__(64) void finalize_kernel(
    const unsigned* __restrict__ max0,
    const float* __restrict__ ork,
    float* __restrict__ out)
{
    int b = threadIdx.x;
    if (b >= 16) return;
    float v = 0.f, bb = 0.f;
    #pragma unroll
    for (int c = 0; c < 8; ++c) {
        float m = fdecode(max0[b * 8 + c]);
        float k = ork[c];
        v  = fmaf(m, k, v);
        bb = fmaf(k, k, bb);
    }
    out[b] = v + bb * TANH_THR - THR_F;
}

// ---------------------------------------------------------------------------
// launcher
// ---------------------------------------------------------------------------
extern "C" void kernel_launch(void* const* d_in, const int* in_sizes, int n_in,
                              void* d_out, int out_size, void* d_ws, size_t ws_size,
                              hipStream_t stream)
{
    const float* nullary = (const float*)d_in[0];   // (16,128)
    const float* unary   = (const float*)d_in[1];   // (16,64,128)
    const float* binary  = (const float*)d_in[2];   // (16,64,63,128)
    const float* andk    = (const float*)d_in[3];   // (3,8,640)
    const float* ork     = (const float*)d_in[4];   // (3,8)
    float* out = (float*)d_out;

    float* ws = (float*)d_ws;
    float*    base = ws;                         // 384
    float*    U0   = ws + 384;                   // 24576
    float*    U1   = ws + 24960;                 // 24576
    float*    Wb   = ws + 49536;                 // 6144
    float*    Wu   = ws + 55680;                 // 6144
    float*    P0   = ws + 61824;                 // 1548288
    float*    P1   = ws + 1610112;               // 1548288
    unsigned* max0 = (unsigned*)(ws + 3158400);  // 128 u32

    prep_kernel<<<480, 64, 0, stream>>>(nullary, andk, Wb, Wu, base, max0);
    proj_kernel<<<1024, 256, 0, stream>>>(unary, binary, Wb, Wu, P0, P1, U0, U1);
    combine_kernel<<<1024, 192, 0, stream>>>(base, U0, U1, P0, P1, ork, max0, out);
    finalize_kernel<<<1, 64, 0, stream>>>(max0, ork, out);
}

// Round 3
// 124.622 us; speedup vs baseline: 1.2989x; 1.0126x over previous
//
#include <hip/hip_runtime.h>

#define THR_F     0.2f
#define TANH_THR  0.19737532f   // tanh(0.2), fp32-rounded

// ---------------------------------------------------------------------------
// helpers
// ---------------------------------------------------------------------------
__device__ __forceinline__ float fast_tanh(float x) {
    x = fminf(10.f, fmaxf(-10.f, x));
    float e = __expf(2.f * x);
    return (e - 1.f) * __builtin_amdgcn_rcpf(e + 1.f);
}

// monotone float <-> uint key for atomicMax on floats
__device__ __forceinline__ unsigned fkey(float f) {
    unsigned u = __float_as_uint(f);
    return (u & 0x80000000u) ? ~u : (u | 0x80000000u);
}
__device__ __forceinline__ float fdecode(unsigned u) {
    return __uint_as_float((u & 0x80000000u) ? (u & 0x7FFFFFFFu) : ~u);
}

// ---------------------------------------------------------------------------
// Kernel 0: prep. Grid = 480 blocks x 64 threads (one wave each).
//  blocks 0..383   : (b,n)=bid -> base[b*24+n] = dot(nullary[b],K[n,0:128])
//                    + THR - ssq[n]*tanh(THR)   (ssq recomputed per block)
//  blocks 384..479 : pack Wb/Wu (6144 elems, 64/block); blocks 384-385 also
//                    zero the 128-entry atomicMax workspace.
// and_kernel layout: (3,8,640) -> ac = a*8+c rows of 640
//   cols 0:128 null | 128:256 u(o0) | 256:384 u(o1) | 384:512 b(o0,j01) | 512:640 b(o1,j10)
// ---------------------------------------------------------------------------
__global__ __launch_bounds__(64) void prep_kernel(
    const float* __restrict__ nullary,   // [16][128]
    const float* __restrict__ andk,      // [24][640]
    float* __restrict__ Wb,              // [128][48] packed binary weights
    float* __restrict__ Wu,              // [128][48] packed unary weights
    float* __restrict__ base,            // [16][24]
    unsigned* __restrict__ max0)         // [16][8]
{
    const int bid = blockIdx.x;
    const int t   = threadIdx.x;
    if (bid < 384) {
        const int b = bid / 24, n = bid % 24;
        const float* w  = andk + n * 640;
        const float* nu = nullary + b * 128;
        float s = 0.f;
        #pragma unroll
        for (int i = 0; i < 10; ++i) { float v = w[t + i * 64]; s = fmaf(v, v, s); }
        float d = fmaf(nu[t], w[t], 0.f);
        d = fmaf(nu[t + 64], w[t + 64], d);
        #pragma unroll
        for (int m = 32; m; m >>= 1) {
            s += __shfl_xor(s, m, 64);
            d += __shfl_xor(d, m, 64);
        }
        if (t == 0) base[bid] = d + THR_F - s * TANH_THR;
    } else {
        const int i = (bid - 384) * 64 + t;   // 0..6143
        const int k = i / 48, n = i % 48;
        const int ac   = (n < 24) ? n : n - 24;
        const int colb = (n < 24) ? 384 : 512;
        const int colu = (n < 24) ? 128 : 256;
        Wb[i] = andk[ac * 640 + colb + k];
        Wu[i] = andk[ac * 640 + colu + k];
        if (bid < 386) max0[(bid - 384) * 64 + t] = 0u;
    }
}

// ---------------------------------------------------------------------------
// Kernel 1: projections. Grid = 1024 blocks x 256 threads (4 waves).
//  blocks 0..1007: binary rows (64 rows/block); 1008..1023: unary rows.
//  Wave w (wave-uniform) computes a 12-channel slice:
//    w=0: P0/U0 ch 0..11, w=1: P0/U0 ch 12..23, w=2: P1/U1 ch 0..11, w=3: ch 12..23
//  Lane = row. Weight pointer is wave-uniform -> scalar (s_load) path.
//  P1 is written TRANSPOSED: P1T[b][j][o1][24] so the combine-stage read
//  (o1 varies across lanes, j fixed) is two contiguous row-runs instead of a
//  6 KB-stride gather. P1T elements are consumed exactly once, so layout is
//  free to choose; the scattered cost moves to these latency-tolerant stores.
// ---------------------------------------------------------------------------
__global__ __launch_bounds__(256) void proj_kernel(
    const float* __restrict__ unary,     // [1024][128]
    const float* __restrict__ binary,    // [64512][128]
    const float* __restrict__ Wb,        // [128][48]
    const float* __restrict__ Wu,        // [128][48]
    float* __restrict__ P0,              // [64512][24]  row = (b,o0,j01)
    float* __restrict__ P1T,             // [16][63][64][24]  (b,j10,o1,ch)
    float* __restrict__ U0, float* __restrict__ U1)   // [1024][24] each
{
    const int bid  = blockIdx.x;
    const int wave = __builtin_amdgcn_readfirstlane((int)(threadIdx.x >> 6)); // 0..3
    const int lane = threadIdx.x & 63;
    const bool is_bin = (bid < 1008);

    const int row = is_bin ? (bid * 64 + lane) : ((bid - 1008) * 64 + lane);
    const float* __restrict__ W   = (is_bin ? Wb : Wu) + wave * 12;
    const float* __restrict__ src = (is_bin ? binary : unary) + (size_t)row * 128;

    float* dst;
    if (is_bin) {
        if (wave < 2) {
            dst = P0 + (size_t)row * 24 + (wave & 1) * 12;
        } else {
            const int b   = row / 4032;          // 64*63
            const int rem = row - b * 4032;
            const int o   = rem / 63;
            const int j   = rem - o * 63;
            dst = P1T + ((size_t)(b * 63 + j) * 64 + o) * 24 + (wave & 1) * 12;
        }
    } else {
        dst = ((wave < 2) ? U0 : U1) + (size_t)row * 24 + (wave & 1) * 12;
    }

    float acc[12];
    #pragma unroll
    for (int n = 0; n < 12; ++n) acc[n] = 0.f;

    const float4* rp = (const float4*)src;
    #pragma unroll 8
    for (int k4 = 0; k4 < 32; ++k4) {
        float4 a = rp[k4];
        const float* wk = W + k4 * 4 * 48;
        #pragma unroll
        for (int q = 0; q < 4; ++q) {
            float av = (q == 0) ? a.x : (q == 1) ? a.y : (q == 2) ? a.z : a.w;
            const float* w = wk + q * 48;
            #pragma unroll
            for (int n = 0; n < 12; ++n) acc[n] = fmaf(av, w[n], acc[n]);
        }
    }

    float4* d4 = (float4*)dst;
    #pragma unroll
    for (int i = 0; i < 3; ++i)
        d4[i] = make_float4(acc[i*4+0], acc[i*4+1], acc[i*4+2], acc[i*4+3]);
}

// ---------------------------------------------------------------------------
// Kernel 2: combine + tanh + reductions + OR stage.
// Grid = 1024 blocks (b,o0) x 192 threads (3 waves). Wave a handles OR-stage a
// (8 channels, ch = a*8) — no inter-wave communication needed:
//   a=0: wave-max over perms -> atomicMax (global max over all perms)
//   a=1: wave-max over o1 -> OR dot -> out1[b,o0]
//   a=2: direct OR dot -> out2[b,o0,j01] per lane
// lane t -> o1 = t + (t>=o0), j01 = t, jrow = o0 - (t<o0).
// All four vector reads (A1, Q0, Q1, out2 write) are now contiguous row-runs.
// ---------------------------------------------------------------------------
__global__ __launch_bounds__(192) void combine_kernel(
    const float* __restrict__ base,   // [16][24]
    const float* __restrict__ U0, const float* __restrict__ U1,  // [1024][24]
    const float* __restrict__ P0,     // [64512][24] (b,o0,j01)
    const float* __restrict__ P1T,    // [16][63][64][24] (b,j10,o1,ch)
    const float* __restrict__ ork,    // [3][8]
    unsigned* __restrict__ max0,      // [16][8]
    float* __restrict__ out)          // [16] + [1024] + [64512]
{
    const int bid = blockIdx.x;
    const int b   = bid >> 6;
    const int o0  = bid & 63;
    const int a   = __builtin_amdgcn_readfirstlane((int)(threadIdx.x >> 6)); // 0..2
    const int t   = threadIdx.x & 63;
    const bool act = (t < 63);

    const int o1   = min(t + (t >= o0 ? 1 : 0), 63);
    const int jrow = min((t < o0) ? (o0 - 1) : o0, 62);   // == j10, clamped for lane 63
    const int j01  = min(t, 62);
    const int ch   = a * 8;

    const float* pb  = base + b * 24 + ch;                                  // uniform
    const float* pa0 = U0 + (size_t)(b * 64 + o0) * 24 + ch;                // uniform
    const float4* A1 = (const float4*)(U1 + (size_t)(b * 64 + o1) * 24 + ch);
    const float4* Q0 = (const float4*)(P0 + (size_t)((b * 64 + o0) * 63 + j01) * 24 + ch);
    const float4* Q1 = (const float4*)(P1T + ((size_t)(b * 63 + jrow) * 64 + o1) * 24 + ch);

    float th[8];
    #pragma unroll
    for (int i = 0; i < 2; ++i) {
        float4 a1 = A1[i], q0 = Q0[i], q1 = Q1[i];
        int n = i * 4;
        th[n+0] = pb[n+0] + pa0[n+0] + a1.x + q0.x + q1.x;
        th[n+1] = pb[n+1] + pa0[n+1] + a1.y + q0.y + q1.y;
        th[n+2] = pb[n+2] + pa0[n+2] + a1.z + q0.z + q1.z;
        th[n+3] = pb[n+3] + pa0[n+3] + a1.w + q0.w + q1.w;
    }
    #pragma unroll
    for (int n = 0; n < 8; ++n) th[n] = fast_tanh(th[n]);

    if (a == 2) {
        if (act) {
            float v = 0.f, b2 = 0.f;
            #pragma unroll
            for (int c = 0; c < 8; ++c) {
                float k = ork[16 + c];
                v  = fmaf(th[c], k, v);
                b2 = fmaf(k, k, b2);
            }
            out[16 + 1024 + ((b * 64 + o0) * 63 + t)] = v + b2 * TANH_THR - THR_F;
        }
        return;
    }

    // mask inactive lane for the max reductions
    if (!act) {
        #pragma unroll
        for (int n = 0; n < 8; ++n) th[n] = -2.0f;
    }
    #pragma unroll
    for (int n = 0; n < 8; ++n) {
        float v = th[n];
        #pragma unroll
        for (int m = 32; m; m >>= 1) v = fmaxf(v, __shfl_xor(v, m, 64));
        th[n] = v;
    }

    if (t == 0) {
        if (a == 1) {
            float v1 = 0.f, b1 = 0.f;
            #pragma unroll
            for (int c = 0; c < 8; ++c) {
                float k = ork[8 + c];
                v1 = fmaf(th[c], k, v1);
                b1 = fmaf(k, k, b1);
            }
            out[16 + b * 64 + o0] = v1 + b1 * TANH_THR - THR_F;
        } else {
            #pragma unroll
            for (int c = 0; c < 8; ++c)
                atomicMax(&max0[b * 8 + c], fkey(th[c]));
        }
    }
}

// ---------------------------------------------------------------------------
// Kernel 3: finalize out0 from the atomicMax workspace
// ---------------------------------------------------------------------------
__global__ __launch_bounds__(64) void finalize_kernel(
    const unsigned* __restrict__ max0,
    const float* __restrict__ ork,
    float* __restrict__ out)
{
    int b = threadIdx.x;
    if (b >= 16) return;
    float v = 0.f, bb = 0.f;
    #pragma unroll
    for (int c = 0; c < 8; ++c) {
        float m = fdecode(max0[b * 8 + c]);
        float k = ork[c];
        v  = fmaf(m, k, v);
        bb = fmaf(k, k, bb);
    }
    out[b] = v + bb * TANH_THR - THR_F;
}

// ---------------------------------------------------------------------------
// launcher
// ---------------------------------------------------------------------------
extern "C" void kernel_launch(void* const* d_in, const int* in_sizes, int n_in,
                              void* d_out, int out_size, void* d_ws, size_t ws_size,
                              hipStream_t stream)
{
    const float* nullary = (const float*)d_in[0];   // (16,128)
    const float* unary   = (const float*)d_in[1];   // (16,64,128)
    const float* binary  = (const float*)d_in[2];   // (16,64,63,128)
    const float* andk    = (const float*)d_in[3];   // (3,8,640)
    const float* ork     = (const float*)d_in[4];   // (3,8)
    float* out = (float*)d_out;

    float* ws = (float*)d_ws;
    float*    base = ws;                         // 384
    float*    U0   = ws + 384;                   // 24576
    float*    U1   = ws + 24960;                 // 24576
    float*    Wb   = ws + 49536;                 // 6144
    float*    Wu   = ws + 55680;                 // 6144
    float*    P0   = ws + 61824;                 // 1548288
    float*    P1T  = ws + 1610112;               // 1548288 (b,j,o1,24 layout)
    unsigned* max0 = (unsigned*)(ws + 3158400);  // 128 u32

    prep_kernel<<<480, 64, 0, stream>>>(nullary, andk, Wb, Wu, base, max0);
    proj_kernel<<<1024, 256, 0, stream>>>(unary, binary, Wb, Wu, P0, P1T, U0, U1);
    combine_kernel<<<1024, 192, 0, stream>>>(base, U0, U1, P0, P1T, ork, max0, out);
    finalize_kernel<<<1, 64, 0, stream>>>(max0, ork, out);
}